// Round 4
// baseline (859.524 us; speedup 1.0000x reference)
//
#include <hip/hip_runtime.h>
#include <cstdint>
#include <cstddef>

typedef __bf16 bf16x8 __attribute__((ext_vector_type(8)));
typedef __bf16 bf16x4 __attribute__((ext_vector_type(4)));
typedef float  f32x4  __attribute__((ext_vector_type(4)));

#define TOKENS  4096
#define SEQLEN  2048
#define HID     2048
#define QKV_W   6144
#define UP_W    8192
#define INTER_  4096

__device__ __forceinline__ void async16(const void* g, void* l) {
  __builtin_amdgcn_global_load_lds(
      (__attribute__((address_space(1))) void*)(g),
      (__attribute__((address_space(3))) void*)(l), 16, 0, 0);
}

// ---------------- fp32 -> bf16 weight convert ----------------
__global__ __launch_bounds__(256) void cvt_kernel(const float* __restrict__ src,
                                                  __bf16* __restrict__ dst, int n4) {
  int i = blockIdx.x * 256 + threadIdx.x;
  if (i >= n4) return;
  float4 f = ((const float4*)src)[i];
  bf16x4 o;
  o[0] = (__bf16)f.x; o[1] = (__bf16)f.y; o[2] = (__bf16)f.z; o[3] = (__bf16)f.w;
  ((bf16x4*)dst)[i] = o;
}

// ---------------- rmsnorm: fp32 in -> bf16 out ----------------
__global__ __launch_bounds__(256) void rmsnorm_kernel(const float* __restrict__ x,
                                                      const float* __restrict__ wgt,
                                                      __bf16* __restrict__ out) {
  const int tok = blockIdx.x;
  const int t = threadIdx.x;
  const float4* xr = (const float4*)(x + (long)tok * HID);
  float4 a = xr[t], b = xr[t + 256];
  float ss = a.x*a.x + a.y*a.y + a.z*a.z + a.w*a.w
           + b.x*b.x + b.y*b.y + b.z*b.z + b.w*b.w;
  #pragma unroll
  for (int off = 32; off; off >>= 1) ss += __shfl_xor(ss, off);
  __shared__ float red[4];
  if ((t & 63) == 0) red[t >> 6] = ss;
  __syncthreads();
  float tot = red[0] + red[1] + red[2] + red[3];
  float r = rsqrtf(tot * (1.0f / HID) + 1e-5f);
  const float4* wr = (const float4*)wgt;
  float4 wa = wr[t], wb = wr[t + 256];
  bf16x4 o0, o1;
  o0[0] = (__bf16)(a.x * r * wa.x); o0[1] = (__bf16)(a.y * r * wa.y);
  o0[2] = (__bf16)(a.z * r * wa.z); o0[3] = (__bf16)(a.w * r * wa.w);
  o1[0] = (__bf16)(b.x * r * wb.x); o1[1] = (__bf16)(b.y * r * wb.y);
  o1[2] = (__bf16)(b.z * r * wb.z); o1[3] = (__bf16)(b.w * r * wb.w);
  bf16x4* orow = (bf16x4*)(out + (long)tok * HID);
  orow[t] = o0; orow[t + 256] = o1;
}

// ---------------- BK=64 bf16 GEMM: C[m,n] = sum_k A[m,k]*B[n,k] ----------------
// BK=64: 32 MFMA per barrier-pair (vs 16 at BK=32) — halves barrier-drain cost.
// LDS 32 KB/block (occupancy stays register-limited ~2.3 blocks/CU).
// ROPE: rotary fused in epilogue for cols < 4096 (pair (i,i+32) -> same lane, acc j/j+2).
// SILU: block computes 64 gate cols + matching 64 value cols of w_up
//       (B rows interleaved 32-wise so gate = acc j(0,1), value = acc j(2,3) same lane);
//       epilogue writes silu(g)*v into a 64-wide act tile.
template<bool OUT_BF16, bool ADD_RES, bool ROPE, bool SILU>
__global__ __launch_bounds__(256) void gemm_bt(const __bf16* __restrict__ A, int lda,
                                               const __bf16* __restrict__ B, int ldb,
                                               void* Cv, int ldc,
                                               const float* __restrict__ Res, int K) {
  __shared__ __align__(16) __bf16 As[128 * 64];
  __shared__ __align__(16) __bf16 Bs[128 * 64];
  const int t = threadIdx.x;
  const int lane = t & 63;
  const int w = t >> 6;
  const int wm = (w >> 1) * 64, wn = (w & 1) * 64;
  const int m0 = blockIdx.y * 128;
  const int n0 = SILU ? blockIdx.x * 64 : blockIdx.x * 128;
  // staging: call c in 0..3 stages tile row c*32 + (t>>3), k-chunk (t&7)*8
  const int sr = t >> 3;          // 0..31
  const int sc = (t & 7) * 8;     // k element offset
  const __bf16* Ag = A + (long)(m0 + sr) * lda + sc;
  const __bf16* Bg = B + (long)(n0 + sr) * ldb + sc;
  char* lA = (char*)As + t * 16;
  char* lB = (char*)Bs + t * 16;
  const int lr = lane & 15;
  const int lq = lane >> 4;
  f32x4 acc[4][4] = {};
  for (int k0 = 0; k0 < K; k0 += 64) {
    __syncthreads();
    #pragma unroll
    for (int c = 0; c < 4; c++)
      async16(Ag + (long)(c * 32) * lda + k0, lA + c * 4096);
    #pragma unroll
    for (int c = 0; c < 4; c++) {
      const long rowoff = SILU ? (long)((c & 1) * INTER_ + (c >> 1) * 32) * ldb
                               : (long)(c * 32) * ldb;
      async16(Bg + rowoff + k0, lB + c * 4096);
    }
    __syncthreads();
    #pragma unroll
    for (int ks = 0; ks < 2; ks++) {
      bf16x8 af[4], bfr[4];
      #pragma unroll
      for (int i = 0; i < 4; i++)
        af[i]  = *(const bf16x8*)(As + (wm + i * 16 + lr) * 64 + ks * 32 + lq * 8);
      #pragma unroll
      for (int j = 0; j < 4; j++)
        bfr[j] = *(const bf16x8*)(Bs + (wn + j * 16 + lr) * 64 + ks * 32 + lq * 8);
      #pragma unroll
      for (int i = 0; i < 4; i++)
        #pragma unroll
        for (int j = 0; j < 4; j++)
          acc[i][j] = __builtin_amdgcn_mfma_f32_16x16x32_bf16(af[i], bfr[j], acc[i][j], 0, 0, 0);
    }
  }
  const int lq4 = lq * 4;
  if (ROPE && n0 < 4096) {
    const float invf0 = exp2f((float)(lr)      * -0.41524101186092029f);
    const float invf1 = exp2f((float)(16 + lr) * -0.41524101186092029f);
    #pragma unroll
    for (int i = 0; i < 4; i++) {
      #pragma unroll
      for (int r = 0; r < 4; r++) {
        const long row = m0 + wm + i * 16 + lq4 + r;
        const float s = (float)(int)(row & (SEQLEN - 1));
        __bf16* crow = (__bf16*)Cv + row * (long)ldc + n0 + wn + lr;
        #pragma unroll
        for (int j = 0; j < 2; j++) {
          float x1 = acc[i][j][r], x2 = acc[i][j + 2][r];
          float ang = s * (j ? invf1 : invf0);
          float sn, cs;
          __sincosf(ang, &sn, &cs);
          crow[j * 16]       = (__bf16)(x1 * cs - x2 * sn);
          crow[(j + 2) * 16] = (__bf16)(x2 * cs + x1 * sn);
        }
      }
    }
  } else if (SILU) {
    #pragma unroll
    for (int i = 0; i < 4; i++) {
      #pragma unroll
      for (int r = 0; r < 4; r++) {
        const long row = m0 + wm + i * 16 + lq4 + r;
        #pragma unroll
        for (int j = 0; j < 2; j++) {
          const long col = n0 + (wn >> 1) + j * 16 + lr;
          float g = acc[i][j][r];
          float v = acc[i][j + 2][r];
          float sg = g / (1.0f + __expf(-g));
          ((__bf16*)Cv)[row * (long)ldc + col] = (__bf16)(sg * v);
        }
      }
    }
  } else {
    #pragma unroll
    for (int i = 0; i < 4; i++) {
      #pragma unroll
      for (int r = 0; r < 4; r++) {
        const long row = m0 + wm + i * 16 + lq4 + r;
        #pragma unroll
        for (int j = 0; j < 4; j++) {
          const long col = n0 + wn + j * 16 + lr;
          float v = acc[i][j][r];
          if (ADD_RES) v += Res[row * (long)ldc + col];
          if (OUT_BF16) ((__bf16*)Cv)[row * (long)ldc + col] = (__bf16)v;
          else          ((float*)Cv)[row * (long)ldc + col] = v;
        }
      }
    }
  }
}

// ---------------- block-local flash attention, single-barrier ----------------
#define VTS 520   // V^T kv-stride (bf16): 1040 B, 16B-aligned
__global__ __launch_bounds__(256) void attn_kernel(const __bf16* __restrict__ qkv,
                                                   __bf16* __restrict__ ctx) {
  const int qt = blockIdx.x;
  const int h  = blockIdx.y;
  const int b  = blockIdx.z;
  const int w    = threadIdx.x >> 6;
  const int lane = threadIdx.x & 63;
  const int lr = lane & 15;
  const int lq = lane >> 4;
  const int q0   = qt * 64;
  const int blk0 = (q0 >> 9) << 9;
  const int nkv  = q0 + 64 - blk0;
  const long tok0 = (long)b * SEQLEN;

  const int qrow = q0 + w * 16 + lr;
  const long qoff = (tok0 + qrow) * QKV_W + h * 64 + lq * 8;
  bf16x8 qf0 = *(const bf16x8*)(qkv + qoff);
  bf16x8 qf1 = *(const bf16x8*)(qkv + qoff + 32);

  __shared__ __align__(16) __bf16 VT[64][VTS];
  __shared__ __align__(16) __bf16 Pb[4][16][48];

  {
    const int vc = (threadIdx.x & 7) * 8;
    for (int kv = threadIdx.x >> 3; kv < nkv; kv += 32) {
      bf16x8 v8 = *(const bf16x8*)(qkv + (tok0 + blk0 + kv) * QKV_W + 2 * HID + h * 64 + vc);
      #pragma unroll
      for (int i = 0; i < 8; i++) VT[vc + i][kv] = v8[i];
    }
  }
  __syncthreads();

  float m[4], l[4];
  f32x4 oacc[4] = {};
  #pragma unroll
  for (int r = 0; r < 4; r++) { m[r] = -1e30f; l[r] = 0.0f; }

  const int myrow = q0 + w * 16 + lq * 4;

  for (int kv0 = 0; kv0 < nkv; kv0 += 32) {
    f32x4 s[2];
    #pragma unroll
    for (int nt = 0; nt < 2; nt++) {
      const long koff = (tok0 + blk0 + kv0 + nt * 16 + lr) * QKV_W + HID + h * 64 + lq * 8;
      bf16x8 kf0 = *(const bf16x8*)(qkv + koff);
      bf16x8 kf1 = *(const bf16x8*)(qkv + koff + 32);
      f32x4 sa = {0.0f, 0.0f, 0.0f, 0.0f};
      sa = __builtin_amdgcn_mfma_f32_16x16x32_bf16(qf0, kf0, sa, 0, 0, 0);
      sa = __builtin_amdgcn_mfma_f32_16x16x32_bf16(qf1, kf1, sa, 0, 0, 0);
      const int kpos = blk0 + kv0 + nt * 16 + lr;
      #pragma unroll
      for (int r = 0; r < 4; r++) {
        float v = sa[r] * 0.125f;
        s[nt][r] = (kpos <= myrow + r) ? v : -1e30f;
      }
    }
    float p0[4], p1[4], alpha[4];
    #pragma unroll
    for (int r = 0; r < 4; r++) {
      float mx = fmaxf(s[0][r], s[1][r]);
      mx = fmaxf(mx, __shfl_xor(mx, 1));
      mx = fmaxf(mx, __shfl_xor(mx, 2));
      mx = fmaxf(mx, __shfl_xor(mx, 4));
      mx = fmaxf(mx, __shfl_xor(mx, 8));
      float mn = fmaxf(m[r], mx);
      alpha[r] = __expf(m[r] - mn);
      m[r] = mn;
      p0[r] = __expf(s[0][r] - mn);
      p1[r] = __expf(s[1][r] - mn);
      float rs = p0[r] + p1[r];
      rs += __shfl_xor(rs, 1);
      rs += __shfl_xor(rs, 2);
      rs += __shfl_xor(rs, 4);
      rs += __shfl_xor(rs, 8);
      l[r] = l[r] * alpha[r] + rs;
    }
    #pragma unroll
    for (int dt = 0; dt < 4; dt++)
      #pragma unroll
      for (int r = 0; r < 4; r++) oacc[dt][r] *= alpha[r];

    #pragma unroll
    for (int r = 0; r < 4; r++) {
      Pb[w][lq * 4 + r][lr]      = (__bf16)p0[r];
      Pb[w][lq * 4 + r][16 + lr] = (__bf16)p1[r];
    }
    asm volatile("s_waitcnt lgkmcnt(0)" ::: "memory");
    bf16x8 pf = *(const bf16x8*)(&Pb[w][lr][lq * 8]);
    #pragma unroll
    for (int dt = 0; dt < 4; dt++) {
      bf16x8 vf = *(const bf16x8*)(&VT[dt * 16 + lr][kv0 + lq * 8]);
      oacc[dt] = __builtin_amdgcn_mfma_f32_16x16x32_bf16(pf, vf, oacc[dt], 0, 0, 0);
    }
  }
  #pragma unroll
  for (int r = 0; r < 4; r++) {
    float inv = 1.0f / l[r];
    long obase = (tok0 + myrow + r) * HID + h * 64;
    #pragma unroll
    for (int dt = 0; dt < 4; dt++)
      ctx[obase + dt * 16 + lr] = (__bf16)(oacc[dt][r] * inv);
  }
}

extern "C" void kernel_launch(void* const* d_in, const int* in_sizes, int n_in,
                              void* d_out, int out_size, void* d_ws, size_t ws_size,
                              hipStream_t stream) {
  const float* x      = (const float*)d_in[0];
  const float* anw    = (const float*)d_in[1];
  const float* fnw    = (const float*)d_in[2];
  const float* w_qkv  = (const float*)d_in[3];
  const float* w_o    = (const float*)d_in[4];
  const float* w_up   = (const float*)d_in[5];
  const float* w_down = (const float*)d_in[6];
  float* out = (float*)d_out;

  char* wsb = (char*)d_ws;
  __bf16* ABUF = (__bf16*)wsb;                        // 16 MiB: h1 / ctx / h2
  __bf16* QKV  = (__bf16*)(wsb + (size_t)16777216);   // 50.3 MiB: qkv; later act (33.5 MiB)
  __bf16* WBUF = (__bf16*)(wsb + (size_t)83886080);   // <=33.5 MiB: bf16 weight scratch
  __bf16* ACT  = QKV;                                  // reuse after attention

  // attention half
  rmsnorm_kernel<<<TOKENS, 256, 0, stream>>>(x, anw, ABUF);
  cvt_kernel<<<(QKV_W * HID / 4 + 255) / 256, 256, 0, stream>>>(w_qkv, WBUF, QKV_W * HID / 4);
  gemm_bt<true, false, true, false><<<dim3(QKV_W / 128, TOKENS / 128), 256, 0, stream>>>(
      ABUF, HID, WBUF, HID, (void*)QKV, QKV_W, nullptr, HID);   // qkv + fused rope
  attn_kernel<<<dim3(SEQLEN / 64, 32, 2), 256, 0, stream>>>(QKV, ABUF);
  cvt_kernel<<<(HID * HID / 4 + 255) / 256, 256, 0, stream>>>(w_o, WBUF, HID * HID / 4);
  gemm_bt<false, true, false, false><<<dim3(HID / 128, TOKENS / 128), 256, 0, stream>>>(
      ABUF, HID, WBUF, HID, (void*)out, HID, x, HID);   // out = x + ctx@w_o^T

  // ffn half
  rmsnorm_kernel<<<TOKENS, 256, 0, stream>>>(out, fnw, ABUF);
  cvt_kernel<<<(UP_W * HID / 4 + 255) / 256, 256, 0, stream>>>(w_up, WBUF, UP_W * HID / 4);
  // fused up+silu: each block does 64 gate cols + matching 64 value cols -> 64 act cols
  gemm_bt<true, false, false, true><<<dim3(INTER_ / 64, TOKENS / 128), 256, 0, stream>>>(
      ABUF, HID, WBUF, HID, (void*)ACT, INTER_, nullptr, HID);
  cvt_kernel<<<(HID * INTER_ / 4 + 255) / 256, 256, 0, stream>>>(w_down, WBUF, HID * INTER_ / 4);
  gemm_bt<false, true, false, false><<<dim3(HID / 128, TOKENS / 128), 256, 0, stream>>>(
      ACT, INTER_, WBUF, INTER_, (void*)out, HID, out, INTER_); // out += act@w_down^T
}

// Round 5
// 751.345 us; speedup vs baseline: 1.1440x; 1.1440x over previous
//
#include <hip/hip_runtime.h>
#include <cstdint>
#include <cstddef>

typedef __bf16 bf16x8 __attribute__((ext_vector_type(8)));
typedef __bf16 bf16x4 __attribute__((ext_vector_type(4)));
typedef float  f32x4  __attribute__((ext_vector_type(4)));

#define TOKENS  4096
#define SEQLEN  2048
#define HID     2048
#define QKV_W   6144
#define UP_W    8192
#define INTER_  4096

__device__ __forceinline__ void async16(const void* g, void* l) {
  __builtin_amdgcn_global_load_lds(
      (__attribute__((address_space(1))) void*)(g),
      (__attribute__((address_space(3))) void*)(l), 16, 0, 0);
}

// ---------------- fp32 -> bf16 weight convert ----------------
__global__ __launch_bounds__(256) void cvt_kernel(const float* __restrict__ src,
                                                  __bf16* __restrict__ dst, int n4) {
  int i = blockIdx.x * 256 + threadIdx.x;
  if (i >= n4) return;
  float4 f = ((const float4*)src)[i];
  bf16x4 o;
  o[0] = (__bf16)f.x; o[1] = (__bf16)f.y; o[2] = (__bf16)f.z; o[3] = (__bf16)f.w;
  ((bf16x4*)dst)[i] = o;
}

// ---------------- rmsnorm: fp32 in -> bf16 out ----------------
__global__ __launch_bounds__(256) void rmsnorm_kernel(const float* __restrict__ x,
                                                      const float* __restrict__ wgt,
                                                      __bf16* __restrict__ out) {
  const int tok = blockIdx.x;
  const int t = threadIdx.x;
  const float4* xr = (const float4*)(x + (long)tok * HID);
  float4 a = xr[t], b = xr[t + 256];
  float ss = a.x*a.x + a.y*a.y + a.z*a.z + a.w*a.w
           + b.x*b.x + b.y*b.y + b.z*b.z + b.w*b.w;
  #pragma unroll
  for (int off = 32; off; off >>= 1) ss += __shfl_xor(ss, off);
  __shared__ float red[4];
  if ((t & 63) == 0) red[t >> 6] = ss;
  __syncthreads();
  float tot = red[0] + red[1] + red[2] + red[3];
  float r = rsqrtf(tot * (1.0f / HID) + 1e-5f);
  const float4* wr = (const float4*)wgt;
  float4 wa = wr[t], wb = wr[t + 256];
  bf16x4 o0, o1;
  o0[0] = (__bf16)(a.x * r * wa.x); o0[1] = (__bf16)(a.y * r * wa.y);
  o0[2] = (__bf16)(a.z * r * wa.z); o0[3] = (__bf16)(a.w * r * wa.w);
  o1[0] = (__bf16)(b.x * r * wb.x); o1[1] = (__bf16)(b.y * r * wb.y);
  o1[2] = (__bf16)(b.z * r * wb.z); o1[3] = (__bf16)(b.w * r * wb.w);
  bf16x4* orow = (bf16x4*)(out + (long)tok * HID);
  orow[t] = o0; orow[t + 256] = o1;
}

// ---------------- BK=64 bf16 GEMM with XOR-swizzled LDS ----------------
// C[m,n] = sum_k A[m,k]*B[n,k] (+Res). BK=64: 32 MFMA per barrier-pair.
// Swizzle: chunk c (16B) of row r stored at LDS position c^(r&7). Staging permutes
// the GLOBAL source per lane (lane t fetches chunk (t&7)^((t>>3)&7)), so the LDS
// destination stays the contiguous base+lane*16 global_load_lds requires.
// Read position (ks*4+lq)^(lr&7) -> 64 lanes spread uniformly over all 32 banks.
// ROPE: rotary fused in epilogue for cols < 4096 (pair (i,i+32) -> same lane, acc j/j+2).
// SILU: block = 64 gate cols + matching 64 value cols (B rows interleaved 32-wise);
//       epilogue writes silu(g)*v into a 64-wide act tile.
template<bool OUT_BF16, bool ADD_RES, bool ROPE, bool SILU>
__global__ __launch_bounds__(256) void gemm_bt(const __bf16* __restrict__ A, int lda,
                                               const __bf16* __restrict__ B, int ldb,
                                               void* Cv, int ldc,
                                               const float* __restrict__ Res, int K) {
  __shared__ __align__(16) __bf16 As[128 * 64];
  __shared__ __align__(16) __bf16 Bs[128 * 64];
  const int t = threadIdx.x;
  const int lane = t & 63;
  const int w = t >> 6;
  const int wm = (w >> 1) * 64, wn = (w & 1) * 64;
  const int m0 = blockIdx.y * 128;
  const int n0 = SILU ? blockIdx.x * 64 : blockIdx.x * 128;
  // staging: slab c stages 32 rows; lane t handles row (t>>3), swizzled k-chunk
  const int sr = t >> 3;                           // row within slab 0..31
  const int sc = (((t & 7) ^ (sr & 7)) * 8);       // swizzled k element offset
  const __bf16* Ag = A + (long)(m0 + sr) * lda + sc;
  const __bf16* Bg = B + (long)(n0 + sr) * ldb + sc;
  char* lA = (char*)As + t * 16;
  char* lB = (char*)Bs + t * 16;
  const int lr = lane & 15;
  const int lq = lane >> 4;
  f32x4 acc[4][4] = {};
  for (int k0 = 0; k0 < K; k0 += 64) {
    __syncthreads();
    #pragma unroll
    for (int c = 0; c < 4; c++)
      async16(Ag + (long)(c * 32) * lda + k0, lA + c * 4096);
    #pragma unroll
    for (int c = 0; c < 4; c++) {
      const long rowoff = SILU ? (long)((c & 1) * INTER_ + (c >> 1) * 32) * ldb
                               : (long)(c * 32) * ldb;
      async16(Bg + rowoff + k0, lB + c * 4096);
    }
    __syncthreads();
    #pragma unroll
    for (int ks = 0; ks < 2; ks++) {
      const int pos = (((ks * 4 + lq) ^ (lr & 7)) * 8);  // swizzled read position
      bf16x8 af[4], bfr[4];
      #pragma unroll
      for (int i = 0; i < 4; i++)
        af[i]  = *(const bf16x8*)(As + (wm + i * 16 + lr) * 64 + pos);
      #pragma unroll
      for (int j = 0; j < 4; j++)
        bfr[j] = *(const bf16x8*)(Bs + (wn + j * 16 + lr) * 64 + pos);
      #pragma unroll
      for (int i = 0; i < 4; i++)
        #pragma unroll
        for (int j = 0; j < 4; j++)
          acc[i][j] = __builtin_amdgcn_mfma_f32_16x16x32_bf16(af[i], bfr[j], acc[i][j], 0, 0, 0);
    }
  }
  const int lq4 = lq * 4;
  if (ROPE && n0 < 4096) {
    const float invf0 = exp2f((float)(lr)      * -0.41524101186092029f);
    const float invf1 = exp2f((float)(16 + lr) * -0.41524101186092029f);
    #pragma unroll
    for (int i = 0; i < 4; i++) {
      #pragma unroll
      for (int r = 0; r < 4; r++) {
        const long row = m0 + wm + i * 16 + lq4 + r;
        const float s = (float)(int)(row & (SEQLEN - 1));
        __bf16* crow = (__bf16*)Cv + row * (long)ldc + n0 + wn + lr;
        #pragma unroll
        for (int j = 0; j < 2; j++) {
          float x1 = acc[i][j][r], x2 = acc[i][j + 2][r];
          float ang = s * (j ? invf1 : invf0);
          float sn, cs;
          __sincosf(ang, &sn, &cs);
          crow[j * 16]       = (__bf16)(x1 * cs - x2 * sn);
          crow[(j + 2) * 16] = (__bf16)(x2 * cs + x1 * sn);
        }
      }
    }
  } else if (SILU) {
    #pragma unroll
    for (int i = 0; i < 4; i++) {
      #pragma unroll
      for (int r = 0; r < 4; r++) {
        const long row = m0 + wm + i * 16 + lq4 + r;
        #pragma unroll
        for (int j = 0; j < 2; j++) {
          const long col = n0 + (wn >> 1) + j * 16 + lr;
          float g = acc[i][j][r];
          float v = acc[i][j + 2][r];
          float sg = g / (1.0f + __expf(-g));
          ((__bf16*)Cv)[row * (long)ldc + col] = (__bf16)(sg * v);
        }
      }
    }
  } else {
    #pragma unroll
    for (int i = 0; i < 4; i++) {
      #pragma unroll
      for (int r = 0; r < 4; r++) {
        const long row = m0 + wm + i * 16 + lq4 + r;
        #pragma unroll
        for (int j = 0; j < 4; j++) {
          const long col = n0 + wn + j * 16 + lr;
          float v = acc[i][j][r];
          if (ADD_RES) v += Res[row * (long)ldc + col];
          if (OUT_BF16) ((__bf16*)Cv)[row * (long)ldc + col] = (__bf16)v;
          else          ((float*)Cv)[row * (long)ldc + col] = v;
        }
      }
    }
  }
}

// ---------------- block-local flash attention, single-barrier ----------------
#define VTS 520   // V^T kv-stride (bf16): 1040 B, 16B-aligned
__global__ __launch_bounds__(256) void attn_kernel(const __bf16* __restrict__ qkv,
                                                   __bf16* __restrict__ ctx) {
  const int qt = blockIdx.x;
  const int h  = blockIdx.y;
  const int b  = blockIdx.z;
  const int w    = threadIdx.x >> 6;
  const int lane = threadIdx.x & 63;
  const int lr = lane & 15;
  const int lq = lane >> 4;
  const int q0   = qt * 64;
  const int blk0 = (q0 >> 9) << 9;
  const int nkv  = q0 + 64 - blk0;
  const long tok0 = (long)b * SEQLEN;

  const int qrow = q0 + w * 16 + lr;
  const long qoff = (tok0 + qrow) * QKV_W + h * 64 + lq * 8;
  bf16x8 qf0 = *(const bf16x8*)(qkv + qoff);
  bf16x8 qf1 = *(const bf16x8*)(qkv + qoff + 32);

  __shared__ __align__(16) __bf16 VT[64][VTS];
  __shared__ __align__(16) __bf16 Pb[4][16][48];

  {
    const int vc = (threadIdx.x & 7) * 8;
    for (int kv = threadIdx.x >> 3; kv < nkv; kv += 32) {
      bf16x8 v8 = *(const bf16x8*)(qkv + (tok0 + blk0 + kv) * QKV_W + 2 * HID + h * 64 + vc);
      #pragma unroll
      for (int i = 0; i < 8; i++) VT[vc + i][kv] = v8[i];
    }
  }
  __syncthreads();

  float m[4], l[4];
  f32x4 oacc[4] = {};
  #pragma unroll
  for (int r = 0; r < 4; r++) { m[r] = -1e30f; l[r] = 0.0f; }

  const int myrow = q0 + w * 16 + lq * 4;

  for (int kv0 = 0; kv0 < nkv; kv0 += 32) {
    f32x4 s[2];
    #pragma unroll
    for (int nt = 0; nt < 2; nt++) {
      const long koff = (tok0 + blk0 + kv0 + nt * 16 + lr) * QKV_W + HID + h * 64 + lq * 8;
      bf16x8 kf0 = *(const bf16x8*)(qkv + koff);
      bf16x8 kf1 = *(const bf16x8*)(qkv + koff + 32);
      f32x4 sa = {0.0f, 0.0f, 0.0f, 0.0f};
      sa = __builtin_amdgcn_mfma_f32_16x16x32_bf16(qf0, kf0, sa, 0, 0, 0);
      sa = __builtin_amdgcn_mfma_f32_16x16x32_bf16(qf1, kf1, sa, 0, 0, 0);
      const int kpos = blk0 + kv0 + nt * 16 + lr;
      #pragma unroll
      for (int r = 0; r < 4; r++) {
        float v = sa[r] * 0.125f;
        s[nt][r] = (kpos <= myrow + r) ? v : -1e30f;
      }
    }
    float p0[4], p1[4], alpha[4];
    #pragma unroll
    for (int r = 0; r < 4; r++) {
      float mx = fmaxf(s[0][r], s[1][r]);
      mx = fmaxf(mx, __shfl_xor(mx, 1));
      mx = fmaxf(mx, __shfl_xor(mx, 2));
      mx = fmaxf(mx, __shfl_xor(mx, 4));
      mx = fmaxf(mx, __shfl_xor(mx, 8));
      float mn = fmaxf(m[r], mx);
      alpha[r] = __expf(m[r] - mn);
      m[r] = mn;
      p0[r] = __expf(s[0][r] - mn);
      p1[r] = __expf(s[1][r] - mn);
      float rs = p0[r] + p1[r];
      rs += __shfl_xor(rs, 1);
      rs += __shfl_xor(rs, 2);
      rs += __shfl_xor(rs, 4);
      rs += __shfl_xor(rs, 8);
      l[r] = l[r] * alpha[r] + rs;
    }
    #pragma unroll
    for (int dt = 0; dt < 4; dt++)
      #pragma unroll
      for (int r = 0; r < 4; r++) oacc[dt][r] *= alpha[r];

    #pragma unroll
    for (int r = 0; r < 4; r++) {
      Pb[w][lq * 4 + r][lr]      = (__bf16)p0[r];
      Pb[w][lq * 4 + r][16 + lr] = (__bf16)p1[r];
    }
    asm volatile("s_waitcnt lgkmcnt(0)" ::: "memory");
    bf16x8 pf = *(const bf16x8*)(&Pb[w][lr][lq * 8]);
    #pragma unroll
    for (int dt = 0; dt < 4; dt++) {
      bf16x8 vf = *(const bf16x8*)(&VT[dt * 16 + lr][kv0 + lq * 8]);
      oacc[dt] = __builtin_amdgcn_mfma_f32_16x16x32_bf16(pf, vf, oacc[dt], 0, 0, 0);
    }
  }
  #pragma unroll
  for (int r = 0; r < 4; r++) {
    float inv = 1.0f / l[r];
    long obase = (tok0 + myrow + r) * HID + h * 64;
    #pragma unroll
    for (int dt = 0; dt < 4; dt++)
      ctx[obase + dt * 16 + lr] = (__bf16)(oacc[dt][r] * inv);
  }
}

extern "C" void kernel_launch(void* const* d_in, const int* in_sizes, int n_in,
                              void* d_out, int out_size, void* d_ws, size_t ws_size,
                              hipStream_t stream) {
  const float* x      = (const float*)d_in[0];
  const float* anw    = (const float*)d_in[1];
  const float* fnw    = (const float*)d_in[2];
  const float* w_qkv  = (const float*)d_in[3];
  const float* w_o    = (const float*)d_in[4];
  const float* w_up   = (const float*)d_in[5];
  const float* w_down = (const float*)d_in[6];
  float* out = (float*)d_out;

  char* wsb = (char*)d_ws;
  __bf16* ABUF = (__bf16*)wsb;                        // 16 MiB: h1 / ctx / h2
  __bf16* QKV  = (__bf16*)(wsb + (size_t)16777216);   // 50.3 MiB: qkv; later act (33.5 MiB)
  __bf16* WBUF = (__bf16*)(wsb + (size_t)83886080);   // <=33.5 MiB: bf16 weight scratch
  __bf16* ACT  = QKV;                                  // reuse after attention

  // attention half
  rmsnorm_kernel<<<TOKENS, 256, 0, stream>>>(x, anw, ABUF);
  cvt_kernel<<<(QKV_W * HID / 4 + 255) / 256, 256, 0, stream>>>(w_qkv, WBUF, QKV_W * HID / 4);
  gemm_bt<true, false, true, false><<<dim3(QKV_W / 128, TOKENS / 128), 256, 0, stream>>>(
      ABUF, HID, WBUF, HID, (void*)QKV, QKV_W, nullptr, HID);   // qkv + fused rope
  attn_kernel<<<dim3(SEQLEN / 64, 32, 2), 256, 0, stream>>>(QKV, ABUF);
  cvt_kernel<<<(HID * HID / 4 + 255) / 256, 256, 0, stream>>>(w_o, WBUF, HID * HID / 4);
  gemm_bt<false, true, false, false><<<dim3(HID / 128, TOKENS / 128), 256, 0, stream>>>(
      ABUF, HID, WBUF, HID, (void*)out, HID, x, HID);   // out = x + ctx@w_o^T

  // ffn half
  rmsnorm_kernel<<<TOKENS, 256, 0, stream>>>(out, fnw, ABUF);
  cvt_kernel<<<(UP_W * HID / 4 + 255) / 256, 256, 0, stream>>>(w_up, WBUF, UP_W * HID / 4);
  // fused up+silu: each block does 64 gate cols + matching 64 value cols -> 64 act cols
  gemm_bt<true, false, false, true><<<dim3(INTER_ / 64, TOKENS / 128), 256, 0, stream>>>(
      ABUF, HID, WBUF, HID, (void*)ACT, INTER_, nullptr, HID);
  cvt_kernel<<<(HID * INTER_ / 4 + 255) / 256, 256, 0, stream>>>(w_down, WBUF, HID * INTER_ / 4);
  gemm_bt<false, true, false, false><<<dim3(HID / 128, TOKENS / 128), 256, 0, stream>>>(
      ACT, INTER_, WBUF, INTER_, (void*)out, HID, out, INTER_); // out += act@w_down^T
}